// Round 7
// baseline (374.101 us; speedup 1.0000x reference)
//
#include <hip/hip_runtime.h>
#include <stdint.h>

#define DIN   768
#define NPROJ 1536           // HID*OUT*2 = 64*12*2
#define SEQ   512
#define NHEAD 12
#define NBATCH 16
#define NEGV  1000000000000.0f

typedef short bf16x8 __attribute__((ext_vector_type(8)));
typedef float f32x4  __attribute__((ext_vector_type(4)));
typedef unsigned short u16x8 __attribute__((ext_vector_type(8)));

__device__ __forceinline__ unsigned short f2bf(float f) {
    union { float f; unsigned int u; } v; v.f = f;
    return (unsigned short)((v.u + 0x7FFFu + ((v.u >> 16) & 1u)) >> 16);  // RTNE
}
__device__ __forceinline__ float bf2f(unsigned short u) {
    union { unsigned int u; float f; } v; v.u = ((unsigned int)u) << 16;
    return v.f;
}

// async global->LDS, 16B/lane (global_load_lds_dwordx4). LDS dest is
// wave-uniform base + lane*16 (m104/m108) — layout must be lane-ordered.
__device__ __forceinline__ void gl_lds16(const unsigned short* g, unsigned short* l) {
    __builtin_amdgcn_global_load_lds(
        (const __attribute__((address_space(1))) unsigned int*)(uintptr_t)g,
        (__attribute__((address_space(3))) unsigned int*)(uintptr_t)l,
        16, 0, 0);
}

// Stage a 128x64-bf16 tile (16 KB) into lds[128*64], XOR-swizzled on the
// GLOBAL side: LDS[row][c16] holds global col16 (c16 ^ (row&7)). Fragment
// reads at col16 cg then use LDS col (cg ^ (row&7)) -> 8 bank-groups across
// 16 lanes = free 2-way conflicts, no padding needed (gl_lds requires none).
__device__ __forceinline__ void stage128x64(const unsigned short* __restrict__ g,
                                            int gstride, unsigned short* lds,
                                            int w, int lane) {
#pragma unroll
    for (int t = 0; t < 4; t++) {
        int lr = w * 32 + t * 8 + (lane >> 3);
        int c16 = (lane & 7) ^ (lr & 7);
        gl_lds16(g + (size_t)lr * gstride + c16 * 8,
                 lds + (w * 32 + t * 8) * 64);
    }
}
__device__ __forceinline__ int swz(int row, int cg) {   // LDS short index
    return row * 64 + ((cg ^ (row & 7)) << 3);
}

// ---- 0) prep: Wt transpose+cast | trig table | X->bf16, one launch ----
__global__ __launch_bounds__(256) void k_prep(const float* __restrict__ X,
                                              unsigned short* __restrict__ Xb,
                                              const float* __restrict__ W,
                                              unsigned short* __restrict__ Wt,
                                              float* __restrict__ trig) {
    __shared__ unsigned short T[64][72];
    const int bid = blockIdx.x, tid = threadIdx.x;
    if (bid < 288) {                       // Wt[n][k] = bf16(W[k][n])
        int n0 = (bid % 24) * 64, k0 = (bid / 24) * 64;
#pragma unroll
        for (int it = 0; it < 4; it++) {
            int c = tid + it * 256;
            int kl = c >> 4, nl = (c & 15) * 4;
            float4 v = *(const float4*)&W[(size_t)(k0 + kl) * NPROJ + n0 + nl];
            T[nl + 0][kl] = f2bf(v.x);
            T[nl + 1][kl] = f2bf(v.y);
            T[nl + 2][kl] = f2bf(v.z);
            T[nl + 3][kl] = f2bf(v.w);
        }
        __syncthreads();
#pragma unroll
        for (int it = 0; it < 2; it++) {
            int c = tid + it * 256;
            int nl = c >> 3, kb = (c & 7) * 8;
            *(int4*)&Wt[(size_t)(n0 + nl) * DIN + k0 + kb] = *(int4*)&T[nl][kb];
        }
        return;
    }
    if (bid < 352) {                       // trig[s][j] = (cos,sin)(s*10000^(-j/32))
        int gi = (bid - 288) * 256 + tid;
        int ss = gi >> 5, j = gi & 31;
        const float C = 0.41524101186092034f;   // log2(10000)/32
        float cs, sn;
        sincosf((float)ss * exp2f(-(float)j * C), &sn, &cs);
        trig[2 * gi]     = cs;
        trig[2 * gi + 1] = sn;
        return;
    }
    int i = ((bid - 352) * 256 + tid) * 4; // X -> bf16
    float4 v = *(const float4*)&X[i];
    short4 s;
    s.x = (short)f2bf(v.x); s.y = (short)f2bf(v.y);
    s.z = (short)f2bf(v.z); s.w = (short)f2bf(v.w);
    *(short4*)&Xb[i] = s;
}

// ---- 1) P = rope( bf16(X@W + b) ), 128x128 tile MFMA, gl_lds staging.
//   1-D grid + bijective XCD remap (neutral but principled). ----
template <bool PRE>
__global__ __launch_bounds__(256) void k_gemm(const float* __restrict__ X,
                                              const unsigned short* __restrict__ Xb,
                                              const unsigned short* __restrict__ Wt,
                                              const float* __restrict__ bias,
                                              const float* __restrict__ trig,
                                              unsigned short* __restrict__ P) {
    __shared__ unsigned short smem[17408];  // sA(8192)|sB(8192); epilogue sT(128x136)
    unsigned short* sA = smem;
    unsigned short* sB = smem + 8192;
    const int tid = threadIdx.x;
    const int bid = blockIdx.x;            // 768 = 8 XCD * 96
    const int xcd = bid & 7, t0 = bid >> 3;
    const int m0 = (xcd + 8 * (t0 / 12)) * 128;
    const int n0 = (t0 % 12) * 128;
    const int lane = tid & 63, w = tid >> 6;
    const int q = lane >> 4, r = lane & 15;
    const int wm = w >> 1, wn = w & 1;
    f32x4 acc[4][4];
#pragma unroll
    for (int i = 0; i < 4; i++)
#pragma unroll
        for (int j = 0; j < 4; j++) acc[i][j] = (f32x4){0.f, 0.f, 0.f, 0.f};

    const unsigned short* Ag = Xb + (size_t)m0 * DIN;
    const unsigned short* Bg = Wt + (size_t)n0 * DIN;

    for (int k0 = 0; k0 < DIN; k0 += 64) {
        __syncthreads();
        if (PRE) {
            stage128x64(Ag + k0, DIN, sA, w, lane);
        } else {
#pragma unroll
            for (int it = 0; it < 4; it++) {
                int c = tid + it * 256;
                int row = c >> 3, c16 = c & 7;
                const float* xp = &X[(size_t)(m0 + row) * DIN + k0 + c16 * 8];
                float4 v0 = *(const float4*)xp;
                float4 v1 = *(const float4*)(xp + 4);
                u16x8 sv;
                sv[0] = f2bf(v0.x); sv[1] = f2bf(v0.y);
                sv[2] = f2bf(v0.z); sv[3] = f2bf(v0.w);
                sv[4] = f2bf(v1.x); sv[5] = f2bf(v1.y);
                sv[6] = f2bf(v1.z); sv[7] = f2bf(v1.w);
                *(u16x8*)&sA[swz(row, c16)] = sv;
            }
        }
        stage128x64(Bg + k0, DIN, sB, w, lane);
        __syncthreads();
#pragma unroll
        for (int kk = 0; kk < 64; kk += 32) {
            const int cg = (kk >> 3) + q;
            bf16x8 af[4], bfr[4];
#pragma unroll
            for (int t = 0; t < 4; t++)
                af[t] = *(const bf16x8*)&sA[swz(wm * 64 + t * 16 + r, cg)];
#pragma unroll
            for (int t = 0; t < 4; t++)
                bfr[t] = *(const bf16x8*)&sB[swz(wn * 64 + t * 16 + r, cg)];
#pragma unroll
            for (int tm = 0; tm < 4; tm++)
#pragma unroll
                for (int tn = 0; tn < 4; tn++)
                    acc[tm][tn] = __builtin_amdgcn_mfma_f32_16x16x32_bf16(
                        af[tm], bfr[tn], acc[tm][tn], 0, 0, 0);
        }
    }
    // epilogue: +bias -> bf16 -> LDS transpose -> RoPE -> int4 stores
    float bb[4];
#pragma unroll
    for (int tn = 0; tn < 4; tn++) bb[tn] = bias[n0 + wn * 64 + tn * 16 + r];
    __syncthreads();
    unsigned short* sT = smem;             // 128 x 136 ushort
#pragma unroll
    for (int tm = 0; tm < 4; tm++) {
        int rowb = wm * 64 + tm * 16 + q * 4;
#pragma unroll
        for (int tn = 0; tn < 4; tn++) {
            int col = wn * 64 + tn * 16 + r;
#pragma unroll
            for (int i = 0; i < 4; i++)
                sT[(rowb + i) * 136 + col] = f2bf(acc[tm][tn][i] + bb[tn]);
        }
    }
    __syncthreads();
#pragma unroll
    for (int it = 0; it < 8; it++) {
        int c = tid + it * 256;
        int row = c >> 4, colb = (c & 15) * 8;
        int m = m0 + row;
        int s = m & (SEQ - 1);
        int base = colb & 31;              // trig j of first channel
        union { int4 v; unsigned short u[8]; } pk;
        pk.v = *(int4*)&sT[row * 136 + colb];
        float wv[8];
#pragma unroll
        for (int j = 0; j < 8; j++) wv[j] = bf2f(pk.u[j]);
        const float* tp = &trig[2 * (s * 32 + base)];
#pragma unroll
        for (int p = 0; p < 4; p++) {
            float4 tt = *(const float4*)&tp[4 * p];  // (cs_e, sn_e, cs_o, sn_o)
            float oe = wv[2 * p] * tt.x - wv[2 * p + 1] * tt.y;
            float oo = wv[2 * p + 1] * tt.z + wv[2 * p] * tt.w;
            pk.u[2 * p]     = f2bf(oe);
            pk.u[2 * p + 1] = f2bf(oo);
        }
        *(int4*)&P[(size_t)m * NPROJ + n0 + colb] = pk.v;
    }
}

// ---- 2) logits: 32-row strips; linear block->address map; K panel in LDS
//   (only chunks overlapping un-masked cols), Q in regs, strip assembled in
//   LDS, one contiguous 64 KB plain-store burst, no trailing barrier.
//   NOTE (r7): launched 3x for attribution — idempotent (reads P/mask only,
//   writes deterministic values), so duplicates are correctness-neutral.
//   dur_us - ~281 == 2 x attn_steady. Reverted next round. ----
__global__ __launch_bounds__(256, 2) void k_attn(const unsigned short* __restrict__ P,
                                                 const float* __restrict__ mask,
                                                 float* __restrict__ out) {
    __shared__ __attribute__((aligned(16))) unsigned short smem[32768];  // 64 KB
    const int tid = threadIdx.x;
    const int bi = blockIdx.x;                // 3072 = 192 groups * 16 strips
    const int g  = bi >> 4, rb = bi & 15;     // linear: bi order == out order
    const int b  = g / NHEAD, h = g % NHEAD;
    const int lane = tid & 63, wn = tid >> 6; // wave wn owns cols [wn*128, +128)
    const int q = lane >> 4, r = lane & 15;
    const int w = wn;
    const size_t obase = ((size_t)((b * NHEAD + h) * SEQ)) * SEQ;
    const int m0 = rb * 32;

    // stage K panel chunks that contain any col n >= 32rb (rest fully masked)
    const unsigned short* Pk = P + (size_t)b * SEQ * NPROJ + h * 128 + 64;
#pragma unroll
    for (int c = 0; c < 4; c++)
        if ((c + 1) * 128 > m0)
            stage128x64(Pk + (size_t)(c * 128) * NPROJ, NPROJ,
                        smem + c * 128 * 64, w, lane);

    // Q fragments straight from global: lane (q,r) row m0+rt*16+r, k=(x2*4+q)*8
    const unsigned short* Pq = P + (size_t)b * SEQ * NPROJ + h * 128;
    bf16x8 qf[2][2];
#pragma unroll
    for (int rt = 0; rt < 2; rt++)
#pragma unroll
        for (int x2 = 0; x2 < 2; x2++)
            qf[rt][x2] = *(const bf16x8*)
                &Pq[(size_t)(m0 + rt * 16 + r) * NPROJ + x2 * 32 + q * 8];

    // mask fragments for my col strip (n = ct*16 + q*4 + j)
    f32x4 mk4[8];
#pragma unroll
    for (int t = 0; t < 8; t++)
        mk4[t] = *(const f32x4*)&mask[b * SEQ + (wn * 8 + t) * 16 + q * 4];

    f32x4 acc[8][2];
#pragma unroll
    for (int t = 0; t < 8; t++) {
        acc[t][0] = (f32x4){0.f, 0.f, 0.f, 0.f};
        acc[t][1] = (f32x4){0.f, 0.f, 0.f, 0.f};
    }

    __syncthreads();   // K chunks resident (drains gl_lds)

    // compute: col-tile ct (16 cols); skip tiles entirely below the diagonal
#pragma unroll
    for (int t = 0; t < 8; t++) {
        const int ct = wn * 8 + t;
        if (ct >= 2 * rb) {            // has any n >= m
            bf16x8 kf[2];
#pragma unroll
            for (int x2 = 0; x2 < 2; x2++)
                kf[x2] = *(const bf16x8*)&smem[swz(ct * 16 + r, x2 * 4 + q)];
#pragma unroll
            for (int x2 = 0; x2 < 2; x2++) {
                acc[t][0] = __builtin_amdgcn_mfma_f32_16x16x32_bf16(
                    kf[x2], qf[0][x2], acc[t][0], 0, 0, 0);
                acc[t][1] = __builtin_amdgcn_mfma_f32_16x16x32_bf16(
                    kf[x2], qf[1][x2], acc[t][1], 0, 0, 0);
            }
        }
    }
    __syncthreads();   // all sK reads done -> reuse smem as f32 strip [32][512]

    float* sOut = (float*)smem;
    // swapped-operand D mapping: m = m0 + rt*16 + r, n = ct*16 + q*4 + i
#pragma unroll
    for (int rt = 0; rt < 2; rt++) {
        const int m = m0 + rt * 16 + r;
#pragma unroll
        for (int t = 0; t < 8; t++) {
            const int ct = wn * 8 + t;
            const int nb = ct * 16 + q * 4;
            f32x4 o;
            if (ct >= 2 * rb) {
#pragma unroll
                for (int j = 0; j < 4; j++)
                    o[j] = (acc[t][rt][j] * mk4[t][j]
                            - (1.f - mk4[t][j]) * NEGV
                            - ((nb + j) < m ? NEGV : 0.f)) * 0.125f;
            } else {                   // fully causal-masked: constants
#pragma unroll
                for (int j = 0; j < 4; j++)
                    o[j] = (-(1.f - mk4[t][j]) * NEGV - NEGV) * 0.125f;
            }
            *(f32x4*)&sOut[(rt * 16 + r) * 512 + nb] = o;
        }
    }
    __syncthreads();
    // stream out: 64 KB fully contiguous, plain stores, no barrier after
    float* od = out + obase + (size_t)m0 * SEQ;
#pragma unroll
    for (int it = 0; it < 16; it++) {
        const int c = tid + it * 256;
        f32x4 v = *(const f32x4*)&sOut[c * 4];
        *(f32x4*)&od[c * 4] = v;
    }
}

extern "C" void kernel_launch(void* const* d_in, const int* in_sizes, int n_in,
                              void* d_out, int out_size, void* d_ws, size_t ws_size,
                              hipStream_t stream) {
    const float* x    = (const float*)d_in[0];   // (16,512,768)
    const float* mask = (const float*)d_in[1];   // (16,512)
    const float* W    = (const float*)d_in[2];   // (768,1536)
    const float* bias = (const float*)d_in[3];   // (1536,)
    float* out = (float*)d_out;                  // (16,12,512,512) fp32

    const size_t wtN   = (size_t)NPROJ * DIN;          // 1.18 M ush
    const size_t pN    = (size_t)NBATCH * SEQ * NPROJ; // 12.58 M ush
    const size_t xN    = (size_t)NBATCH * SEQ * DIN;   // 6.29 M ush
    const size_t trigN = (size_t)SEQ * 32 * 2;         // 32 K floats
    unsigned short* Wt = (unsigned short*)d_ws;
    unsigned short* P  = Wt + wtN;
    float* trig        = (float*)(P + pN);
    unsigned short* Xb = (unsigned short*)(trig + trigN);
    const bool pre = ws_size >= (wtN + pN + xN) * sizeof(unsigned short)
                               + trigN * sizeof(float);

    const int xblocks = (int)(xN / 1024);    // 6144
    k_prep<<<pre ? (352 + xblocks) : 352, 256, 0, stream>>>(x, Xb, W, Wt, trig);
    if (pre) {
        k_gemm<true><<<dim3(768), 256, 0, stream>>>(x, Xb, Wt, bias, trig, P);
    } else {
        k_gemm<false><<<dim3(768), 256, 0, stream>>>(x, nullptr, Wt, bias, trig, P);
    }
    // ATTRIBUTION (r7): k_attn is idempotent -> run 3x. dur_us increase over
    // the ~281 baseline = 2 x steady-state attn time. Reverted next round.
    k_attn<<<dim3(NBATCH * NHEAD * (SEQ / 32)), 256, 0, stream>>>(P, mask, out);
    k_attn<<<dim3(NBATCH * NHEAD * (SEQ / 32)), 256, 0, stream>>>(P, mask, out);
    k_attn<<<dim3(NBATCH * NHEAD * (SEQ / 32)), 256, 0, stream>>>(P, mask, out);
}

// Round 10
// 276.546 us; speedup vs baseline: 1.3528x; 1.3528x over previous
//
#include <hip/hip_runtime.h>
#include <stdint.h>

#define DIN   768
#define NPROJ 1536           // HID*OUT*2 = 64*12*2
#define SEQ   512
#define NHEAD 12
#define NBATCH 16
#define NEGV  1000000000000.0f

typedef short bf16x8 __attribute__((ext_vector_type(8)));
typedef float f32x4  __attribute__((ext_vector_type(4)));
typedef unsigned short u16x8 __attribute__((ext_vector_type(8)));

__device__ __forceinline__ unsigned short f2bf(float f) {
    union { float f; unsigned int u; } v; v.f = f;
    return (unsigned short)((v.u + 0x7FFFu + ((v.u >> 16) & 1u)) >> 16);  // RTNE
}
__device__ __forceinline__ float bf2f(unsigned short u) {
    union { unsigned int u; float f; } v; v.u = ((unsigned int)u) << 16;
    return v.f;
}

// async global->LDS, 16B/lane (global_load_lds_dwordx4). LDS dest is
// wave-uniform base + lane*16 (m104/m108) — layout must be lane-ordered.
__device__ __forceinline__ void gl_lds16(const unsigned short* g, unsigned short* l) {
    __builtin_amdgcn_global_load_lds(
        (const __attribute__((address_space(1))) unsigned int*)(uintptr_t)g,
        (__attribute__((address_space(3))) unsigned int*)(uintptr_t)l,
        16, 0, 0);
}

// Stage a 128x64-bf16 tile (16 KB) into lds[128*64], XOR-swizzled on the
// GLOBAL side: LDS[row][c16] holds global col16 (c16 ^ (row&7)). Fragment
// reads at col16 cg then use LDS col (cg ^ (row&7)) -> 8 bank-groups across
// 16 lanes = free 2-way conflicts, no padding needed (gl_lds requires none).
__device__ __forceinline__ void stage128x64(const unsigned short* __restrict__ g,
                                            int gstride, unsigned short* lds,
                                            int w, int lane) {
#pragma unroll
    for (int t = 0; t < 4; t++) {
        int lr = w * 32 + t * 8 + (lane >> 3);
        int c16 = (lane & 7) ^ (lr & 7);
        gl_lds16(g + (size_t)lr * gstride + c16 * 8,
                 lds + (w * 32 + t * 8) * 64);
    }
}
__device__ __forceinline__ int swz(int row, int cg) {   // LDS short index
    return row * 64 + ((cg ^ (row & 7)) << 3);
}

// A-tile staging for k_gemm<false>: f32 X -> bf16 into swizzled LDS buf.
__device__ __forceinline__ void stageA_cast(const float* __restrict__ X,
                                            int m0, int k0,
                                            unsigned short* buf, int tid) {
#pragma unroll
    for (int it = 0; it < 4; it++) {
        int c = tid + it * 256;
        int row = c >> 3, c16 = c & 7;
        const float* xp = &X[(size_t)(m0 + row) * DIN + k0 + c16 * 8];
        float4 v0 = *(const float4*)xp;
        float4 v1 = *(const float4*)(xp + 4);
        u16x8 sv;
        sv[0] = f2bf(v0.x); sv[1] = f2bf(v0.y);
        sv[2] = f2bf(v0.z); sv[3] = f2bf(v0.w);
        sv[4] = f2bf(v1.x); sv[5] = f2bf(v1.y);
        sv[6] = f2bf(v1.z); sv[7] = f2bf(v1.w);
        *(u16x8*)&buf[swz(row, c16)] = sv;
    }
}

// ---- 0) prep: Wt transpose+cast | trig table | X->bf16, one launch ----
__global__ __launch_bounds__(256) void k_prep(const float* __restrict__ X,
                                              unsigned short* __restrict__ Xb,
                                              const float* __restrict__ W,
                                              unsigned short* __restrict__ Wt,
                                              float* __restrict__ trig) {
    __shared__ unsigned short T[64][72];
    const int bid = blockIdx.x, tid = threadIdx.x;
    if (bid < 288) {                       // Wt[n][k] = bf16(W[k][n])
        int n0 = (bid % 24) * 64, k0 = (bid / 24) * 64;
#pragma unroll
        for (int it = 0; it < 4; it++) {
            int c = tid + it * 256;
            int kl = c >> 4, nl = (c & 15) * 4;
            float4 v = *(const float4*)&W[(size_t)(k0 + kl) * NPROJ + n0 + nl];
            T[nl + 0][kl] = f2bf(v.x);
            T[nl + 1][kl] = f2bf(v.y);
            T[nl + 2][kl] = f2bf(v.z);
            T[nl + 3][kl] = f2bf(v.w);
        }
        __syncthreads();
#pragma unroll
        for (int it = 0; it < 2; it++) {
            int c = tid + it * 256;
            int nl = c >> 3, kb = (c & 7) * 8;
            *(int4*)&Wt[(size_t)(n0 + nl) * DIN + k0 + kb] = *(int4*)&T[nl][kb];
        }
        return;
    }
    if (bid < 352) {                       // trig[s][j] = (cos,sin)(s*10000^(-j/32))
        int gi = (bid - 288) * 256 + tid;
        int ss = gi >> 5, j = gi & 31;
        const float C = 0.41524101186092034f;   // log2(10000)/32
        float cs, sn;
        sincosf((float)ss * exp2f(-(float)j * C), &sn, &cs);
        trig[2 * gi]     = cs;
        trig[2 * gi + 1] = sn;
        return;
    }
    int i = ((bid - 352) * 256 + tid) * 4; // X -> bf16
    float4 v = *(const float4*)&X[i];
    short4 s;
    s.x = (short)f2bf(v.x); s.y = (short)f2bf(v.y);
    s.z = (short)f2bf(v.z); s.w = (short)f2bf(v.w);
    *(short4*)&Xb[i] = s;
}

// ---- 1) P = rope( bf16(X@W + b) ), 128x128 tile MFMA.
//   r10: 2-phase double-buffered K-loop (no lambda): prologue stage+barrier;
//   loop { stage(next->buf^1); ds_read+MFMA(buf); __syncthreads }. One
//   barrier/K-step (was 2); staging latency hidden under the MFMA phase so
//   the barrier's vmcnt(0) drain is cheap. LDS 64 KB -> 2 blocks/CU. ----
template <bool PRE>
__global__ __launch_bounds__(256) void k_gemm(const float* __restrict__ X,
                                              const unsigned short* __restrict__ Xb,
                                              const unsigned short* __restrict__ Wt,
                                              const float* __restrict__ bias,
                                              const float* __restrict__ trig,
                                              unsigned short* __restrict__ P) {
    __shared__ unsigned short smem[32768];  // 2 x (A 8192 | B 8192); sT reuses
    const int tid = threadIdx.x;
    const int bid = blockIdx.x;            // 768 = 8 XCD * 96
    const int xcd = bid & 7, t0 = bid >> 3;
    const int m0 = (xcd + 8 * (t0 / 12)) * 128;
    const int n0 = (t0 % 12) * 128;
    const int lane = tid & 63, w = tid >> 6;
    const int q = lane >> 4, r = lane & 15;
    const int wm = w >> 1, wn = w & 1;
    f32x4 acc[4][4];
#pragma unroll
    for (int i = 0; i < 4; i++)
#pragma unroll
        for (int j = 0; j < 4; j++) acc[i][j] = (f32x4){0.f, 0.f, 0.f, 0.f};

    const unsigned short* Ag = Xb + (size_t)m0 * DIN;
    const unsigned short* Bg = Wt + (size_t)n0 * DIN;

    // prologue: stage K-step 0 into buf 0; barrier drains it
    if (PRE) stage128x64(Ag, DIN, smem, w, lane);
    else     stageA_cast(X, m0, 0, smem, tid);
    stage128x64(Bg, DIN, smem + 8192, w, lane);
    __syncthreads();

    for (int it = 0; it < 12; ++it) {
        const int c = it & 1;
        unsigned short* sAc = smem + c * 16384;
        unsigned short* sBc = sAc + 8192;
        if (it + 1 < 12) {                 // issue next-tile stage EARLY
            unsigned short* nxt = smem + (c ^ 1) * 16384;
            if (PRE) stage128x64(Ag + (it + 1) * 64, DIN, nxt, w, lane);
            else     stageA_cast(X, m0, (it + 1) * 64, nxt, tid);
            stage128x64(Bg + (it + 1) * 64, DIN, nxt + 8192, w, lane);
        }
        // compute current tile (covers the in-flight stage latency)
#pragma unroll
        for (int kk = 0; kk < 64; kk += 32) {
            const int cg = (kk >> 3) + q;
            bf16x8 af[4], bfr[4];
#pragma unroll
            for (int t = 0; t < 4; t++)
                af[t] = *(const bf16x8*)&sAc[swz(wm * 64 + t * 16 + r, cg)];
#pragma unroll
            for (int t = 0; t < 4; t++)
                bfr[t] = *(const bf16x8*)&sBc[swz(wn * 64 + t * 16 + r, cg)];
#pragma unroll
            for (int tm = 0; tm < 4; tm++)
#pragma unroll
                for (int tn = 0; tn < 4; tn++)
                    acc[tm][tn] = __builtin_amdgcn_mfma_f32_16x16x32_bf16(
                        af[tm], bfr[tn], acc[tm][tn], 0, 0, 0);
        }
        __syncthreads();                   // next buffer ready; one barrier/step
    }
    // epilogue: +bias -> bf16 -> LDS transpose -> RoPE -> int4 stores
    float bb[4];
#pragma unroll
    for (int tn = 0; tn < 4; tn++) bb[tn] = bias[n0 + wn * 64 + tn * 16 + r];
    unsigned short* sT = smem;             // 128 x 136 ushort (34 KB, fits)
#pragma unroll
    for (int tm = 0; tm < 4; tm++) {
        int rowb = wm * 64 + tm * 16 + q * 4;
#pragma unroll
        for (int tn = 0; tn < 4; tn++) {
            int col = wn * 64 + tn * 16 + r;
#pragma unroll
            for (int i = 0; i < 4; i++)
                sT[(rowb + i) * 136 + col] = f2bf(acc[tm][tn][i] + bb[tn]);
        }
    }
    __syncthreads();
#pragma unroll
    for (int it = 0; it < 8; it++) {
        int c = tid + it * 256;
        int row = c >> 4, colb = (c & 15) * 8;
        int m = m0 + row;
        int s = m & (SEQ - 1);
        int base = colb & 31;              // trig j of first channel
        union { int4 v; unsigned short u[8]; } pk;
        pk.v = *(int4*)&sT[row * 136 + colb];
        float wv[8];
#pragma unroll
        for (int j = 0; j < 8; j++) wv[j] = bf2f(pk.u[j]);
        const float* tp = &trig[2 * (s * 32 + base)];
#pragma unroll
        for (int p = 0; p < 4; p++) {
            float4 tt = *(const float4*)&tp[4 * p];  // (cs_e, sn_e, cs_o, sn_o)
            float oe = wv[2 * p] * tt.x - wv[2 * p + 1] * tt.y;
            float oo = wv[2 * p + 1] * tt.z + wv[2 * p] * tt.w;
            pk.u[2 * p]     = f2bf(oe);
            pk.u[2 * p + 1] = f2bf(oo);
        }
        *(int4*)&P[(size_t)m * NPROJ + n0 + colb] = pk.v;
    }
}

// ---- 2) logits: 32-row strips; linear block->address map; K panel in LDS
//   (only chunks overlapping un-masked cols), Q in regs, strip assembled in
//   LDS, one contiguous 64 KB plain-store burst, no trailing barrier.
//   Steady-state 46.2 us (r7 duplicate-launch attribution), ~78% of the
//   ~36 us write floor. ----
__global__ __launch_bounds__(256, 2) void k_attn(const unsigned short* __restrict__ P,
                                                 const float* __restrict__ mask,
                                                 float* __restrict__ out) {
    __shared__ __attribute__((aligned(16))) unsigned short smem[32768];  // 64 KB
    const int tid = threadIdx.x;
    const int bi = blockIdx.x;                // 3072 = 192 groups * 16 strips
    const int g  = bi >> 4, rb = bi & 15;     // linear: bi order == out order
    const int b  = g / NHEAD, h = g % NHEAD;
    const int lane = tid & 63, wn = tid >> 6; // wave wn owns cols [wn*128, +128)
    const int q = lane >> 4, r = lane & 15;
    const int w = wn;
    const size_t obase = ((size_t)((b * NHEAD + h) * SEQ)) * SEQ;
    const int m0 = rb * 32;

    // stage K panel chunks that contain any col n >= 32rb (rest fully masked)
    const unsigned short* Pk = P + (size_t)b * SEQ * NPROJ + h * 128 + 64;
#pragma unroll
    for (int c = 0; c < 4; c++)
        if ((c + 1) * 128 > m0)
            stage128x64(Pk + (size_t)(c * 128) * NPROJ, NPROJ,
                        smem + c * 128 * 64, w, lane);

    // Q fragments straight from global: lane (q,r) row m0+rt*16+r, k=(x2*4+q)*8
    const unsigned short* Pq = P + (size_t)b * SEQ * NPROJ + h * 128;
    bf16x8 qf[2][2];
#pragma unroll
    for (int rt = 0; rt < 2; rt++)
#pragma unroll
        for (int x2 = 0; x2 < 2; x2++)
            qf[rt][x2] = *(const bf16x8*)
                &Pq[(size_t)(m0 + rt * 16 + r) * NPROJ + x2 * 32 + q * 8];

    // mask fragments for my col strip (n = ct*16 + q*4 + j)
    f32x4 mk4[8];
#pragma unroll
    for (int t = 0; t < 8; t++)
        mk4[t] = *(const f32x4*)&mask[b * SEQ + (wn * 8 + t) * 16 + q * 4];

    f32x4 acc[8][2];
#pragma unroll
    for (int t = 0; t < 8; t++) {
        acc[t][0] = (f32x4){0.f, 0.f, 0.f, 0.f};
        acc[t][1] = (f32x4){0.f, 0.f, 0.f, 0.f};
    }

    __syncthreads();   // K chunks resident (drains gl_lds)

    // compute: col-tile ct (16 cols); skip tiles entirely below the diagonal
#pragma unroll
    for (int t = 0; t < 8; t++) {
        const int ct = wn * 8 + t;
        if (ct >= 2 * rb) {            // has any n >= m
            bf16x8 kf[2];
#pragma unroll
            for (int x2 = 0; x2 < 2; x2++)
                kf[x2] = *(const bf16x8*)&smem[swz(ct * 16 + r, x2 * 4 + q)];
#pragma unroll
            for (int x2 = 0; x2 < 2; x2++) {
                acc[t][0] = __builtin_amdgcn_mfma_f32_16x16x32_bf16(
                    kf[x2], qf[0][x2], acc[t][0], 0, 0, 0);
                acc[t][1] = __builtin_amdgcn_mfma_f32_16x16x32_bf16(
                    kf[x2], qf[1][x2], acc[t][1], 0, 0, 0);
            }
        }
    }
    __syncthreads();   // all sK reads done -> reuse smem as f32 strip [32][512]

    float* sOut = (float*)smem;
    // swapped-operand D mapping: m = m0 + rt*16 + r, n = ct*16 + q*4 + i
#pragma unroll
    for (int rt = 0; rt < 2; rt++) {
        const int m = m0 + rt * 16 + r;
#pragma unroll
        for (int t = 0; t < 8; t++) {
            const int ct = wn * 8 + t;
            const int nb = ct * 16 + q * 4;
            f32x4 o;
            if (ct >= 2 * rb) {
#pragma unroll
                for (int j = 0; j < 4; j++)
                    o[j] = (acc[t][rt][j] * mk4[t][j]
                            - (1.f - mk4[t][j]) * NEGV
                            - ((nb + j) < m ? NEGV : 0.f)) * 0.125f;
            } else {                   // fully causal-masked: constants
#pragma unroll
                for (int j = 0; j < 4; j++)
                    o[j] = (-(1.f - mk4[t][j]) * NEGV - NEGV) * 0.125f;
            }
            *(f32x4*)&sOut[(rt * 16 + r) * 512 + nb] = o;
        }
    }
    __syncthreads();
    // stream out: 64 KB fully contiguous, plain stores, no barrier after
    float* od = out + obase + (size_t)m0 * SEQ;
#pragma unroll
    for (int it = 0; it < 16; it++) {
        const int c = tid + it * 256;
        f32x4 v = *(const f32x4*)&sOut[c * 4];
        *(f32x4*)&od[c * 4] = v;
    }
}

extern "C" void kernel_launch(void* const* d_in, const int* in_sizes, int n_in,
                              void* d_out, int out_size, void* d_ws, size_t ws_size,
                              hipStream_t stream) {
    const float* x    = (const float*)d_in[0];   // (16,512,768)
    const float* mask = (const float*)d_in[1];   // (16,512)
    const float* W    = (const float*)d_in[2];   // (768,1536)
    const float* bias = (const float*)d_in[3];   // (1536,)
    float* out = (float*)d_out;                  // (16,12,512,512) fp32

    const size_t wtN   = (size_t)NPROJ * DIN;          // 1.18 M ush
    const size_t pN    = (size_t)NBATCH * SEQ * NPROJ; // 12.58 M ush
    const size_t xN    = (size_t)NBATCH * SEQ * DIN;   // 6.29 M ush
    const size_t trigN = (size_t)SEQ * 32 * 2;         // 32 K floats
    unsigned short* Wt = (unsigned short*)d_ws;
    unsigned short* P  = Wt + wtN;
    float* trig        = (float*)(P + pN);
    unsigned short* Xb = (unsigned short*)(trig + trigN);
    const bool pre = ws_size >= (wtN + pN + xN) * sizeof(unsigned short)
                               + trigN * sizeof(float);

    const int xblocks = (int)(xN / 1024);    // 6144
    k_prep<<<pre ? (352 + xblocks) : 352, 256, 0, stream>>>(x, Xb, W, Wt, trig);
    if (pre) {
        k_gemm<true><<<dim3(768), 256, 0, stream>>>(x, Xb, Wt, bias, trig, P);
    } else {
        k_gemm<false><<<dim3(768), 256, 0, stream>>>(x, nullptr, Wt, bias, trig, P);
    }
    k_attn<<<dim3(NBATCH * NHEAD * (SEQ / 32)), 256, 0, stream>>>(P, mask, out);
}